// Round 1
// baseline (1602.171 us; speedup 1.0000x reference)
//
#include <hip/hip_runtime.h>
#include <cmath>

// MLPTexture3D: 16-level hashgrid encode (tcnn-style) + 32->32->32->4 MLP.
// Baseline: one thread per point; all level features + MLP in registers.
// Level params (scale/res/dense) computed host-side in double to match numpy.

namespace {
constexpr int kLevels = 16;
constexpr unsigned kTableSize = 1u << 19;  // LOG2_HASHMAP = 19

struct LevelParams {
  float scale[kLevels];
  unsigned res[kLevels];
  int dense[kLevels];
};
}  // namespace

__global__ __launch_bounds__(256)
void hashgrid_mlp_kernel(const float* __restrict__ points,
                         const float* __restrict__ tables,
                         const float* __restrict__ W1,
                         const float* __restrict__ W2,
                         const float* __restrict__ W3,
                         const float* __restrict__ aabb,
                         float* __restrict__ out,
                         LevelParams lp, int n)
{
  int i = blockIdx.x * blockDim.x + threadIdx.x;
  if (i >= n) return;

  // aabb: [2,3] row-major: [min_xyz, max_xyz]
  float a0x = aabb[0], a0y = aabb[1], a0z = aabb[2];
  float a1x = aabb[3], a1y = aabb[4], a1z = aabb[5];
  float px = points[3 * i + 0];
  float py = points[3 * i + 1];
  float pz = points[3 * i + 2];
  float x = fminf(fmaxf((px - a0x) / (a1x - a0x), 0.f), 1.f);
  float y = fminf(fmaxf((py - a0y) / (a1y - a0y), 0.f), 1.f);
  float z = fminf(fmaxf((pz - a0z) / (a1z - a0z), 0.f), 1.f);

  float enc[2 * kLevels];

  // Level loop MUST be fully unrolled so enc[] stays in registers.
  #pragma unroll
  for (int l = 0; l < kLevels; ++l) {
    float s = lp.scale[l];
    unsigned res = lp.res[l];
    bool dense = (lp.dense[l] != 0);
    unsigned rm1 = res - 1u;
    unsigned res2 = res * res;

    float fx = x * s + 0.5f;
    float fy = y * s + 0.5f;
    float fz = z * s + 0.5f;
    float fx0 = floorf(fx), fy0 = floorf(fy), fz0 = floorf(fz);
    float wx = fx - fx0, wy = fy - fy0, wz = fz - fz0;
    unsigned bx = (unsigned)fx0, by = (unsigned)fy0, bz = (unsigned)fz0;

    const float2* tab = reinterpret_cast<const float2*>(tables) + (size_t)l * kTableSize;

    float acc0 = 0.f, acc1 = 0.f;
    #pragma unroll
    for (int c = 0; c < 8; ++c) {
      unsigned ox = (unsigned)(c & 1);
      unsigned oy = (unsigned)((c >> 1) & 1);
      unsigned oz = (unsigned)((c >> 2) & 1);
      unsigned pcx = min(bx + ox, rm1);
      unsigned pcy = min(by + oy, rm1);
      unsigned pcz = min(bz + oz, rm1);
      unsigned idx;
      if (dense) {
        idx = pcx + pcy * res + pcz * res2;
      } else {
        idx = (pcx ^ (pcy * 2654435761u) ^ (pcz * 805459861u)) & (kTableSize - 1u);
      }
      float wt = (ox ? wx : 1.f - wx) * (oy ? wy : 1.f - wy) * (oz ? wz : 1.f - wz);
      float2 f = tab[idx];
      acc0 += wt * f.x;
      acc1 += wt * f.y;
    }
    enc[2 * l + 0] = acc0;
    enc[2 * l + 1] = acc1;
  }

  // MLP: h1 = relu(enc @ W1^T); h2 = relu(h1 @ W2^T); o = h2 @ W3^T
  // Weights are wave-uniform with constant indices -> compiler emits s_load;
  // FMAs take one SGPR operand each (no LDS round-trip needed).
  float h1[32];
  #pragma unroll
  for (int j = 0; j < 32; ++j) {
    float acc = 0.f;
    #pragma unroll
    for (int k = 0; k < 32; ++k) acc += enc[k] * W1[32 * j + k];
    h1[j] = fmaxf(acc, 0.f);
  }
  float h2[32];
  #pragma unroll
  for (int j = 0; j < 32; ++j) {
    float acc = 0.f;
    #pragma unroll
    for (int k = 0; k < 32; ++k) acc += h1[k] * W2[32 * j + k];
    h2[j] = fmaxf(acc, 0.f);
  }
  float o[4];
  #pragma unroll
  for (int j = 0; j < 4; ++j) {
    float acc = 0.f;
    #pragma unroll
    for (int k = 0; k < 32; ++k) acc += h2[k] * W3[32 * j + k];
    o[j] = acc;
  }

  // sigmoid(o) * (mx - mn) + mn ; mn=[0,0,0,0.01], mx=[1,1,1,1]
  float4 r;
  r.x = 1.f / (1.f + __expf(-o[0]));
  r.y = 1.f / (1.f + __expf(-o[1]));
  r.z = 1.f / (1.f + __expf(-o[2]));
  r.w = 0.99f / (1.f + __expf(-o[3])) + 0.01f;
  reinterpret_cast<float4*>(out)[i] = r;
}

extern "C" void kernel_launch(void* const* d_in, const int* in_sizes, int n_in,
                              void* d_out, int out_size, void* d_ws, size_t ws_size,
                              hipStream_t stream) {
  const float* points = (const float*)d_in[0];
  const float* tables = (const float*)d_in[1];
  const float* W1     = (const float*)d_in[2];
  const float* W2     = (const float*)d_in[3];
  const float* W3     = (const float*)d_in[4];
  const float* aabb   = (const float*)d_in[5];
  float* out = (float*)d_out;
  int n = in_sizes[0] / 3;

  // Match reference double-precision level math exactly:
  // PER_LEVEL_SCALE = exp(log(4096/16)/15); scale_l = 16*PLS^l - 1
  LevelParams lp;
  const double pls = std::exp(std::log(4096.0 / 16.0) / 15.0);
  for (int l = 0; l < kLevels; ++l) {
    double s = 16.0 * std::pow(pls, (double)l) - 1.0;
    lp.scale[l] = (float)s;
    long long res = (long long)std::ceil(s) + 1;
    lp.res[l] = (unsigned)res;
    lp.dense[l] = (res * res * res <= (long long)kTableSize) ? 1 : 0;
  }

  const int block = 256;
  const int grid = (n + block - 1) / block;
  hipLaunchKernelGGL(hashgrid_mlp_kernel, dim3(grid), dim3(block), 0, stream,
                     points, tables, W1, W2, W3, aabb, out, lp, n);
}

// Round 2
// 984.252 us; speedup vs baseline: 1.6278x; 1.6278x over previous
//
#include <hip/hip_runtime.h>
#include <hip/hip_fp16.h>
#include <cmath>

// MLPTexture3D: 16-level hashgrid encode + 32->32->32->4 MLP.
// R1: level-phased gather for L2 locality.
//   k0: tables fp32 -> fp16 into ws (2 MB/level fits per-XCD 4 MB L2)
//   k1: encode, one (level, point) per thread; level = blockIdx/bpl so the
//       dispatcher serializes levels -> one table hot in L2 at a time.
//       enc written to ws as half2 [L][N] (coalesced 4 B/lane).
//   k2: MLP from enc, fp32 FMAs with SGPR-resident weights.
// Fallback: monolithic R0 kernel if ws_size too small.

namespace {
constexpr int kLevels = 16;
constexpr unsigned kTableSize = 1u << 19;

struct LevelParams {
  float scale[kLevels];
  unsigned res[kLevels];
  int dense[kLevels];
};
}  // namespace

// ---------------- k0: table conversion ----------------
__global__ __launch_bounds__(256)
void conv_tables_kernel(const float2* __restrict__ src, __half2* __restrict__ dst,
                        int n_entries)
{
  int i = blockIdx.x * blockDim.x + threadIdx.x;
  int stride = gridDim.x * blockDim.x;
  for (; i < n_entries; i += stride) {
    float2 v = src[i];
    dst[i] = __floats2half2_rn(v.x, v.y);
  }
}

// ---------------- k1: level-phased encode ----------------
__global__ __launch_bounds__(256)
void encode_kernel(const float* __restrict__ points,
                   const __half2* __restrict__ tables,
                   const float* __restrict__ aabb,
                   __half2* __restrict__ enc,   // [L][N]
                   LevelParams lp, int n, int bpl)
{
  int l = blockIdx.x / bpl;
  int i = (blockIdx.x - l * bpl) * blockDim.x + threadIdx.x;
  if (i >= n) return;

  float a0x = aabb[0], a0y = aabb[1], a0z = aabb[2];
  float a1x = aabb[3], a1y = aabb[4], a1z = aabb[5];
  float x = fminf(fmaxf((points[3 * i + 0] - a0x) / (a1x - a0x), 0.f), 1.f);
  float y = fminf(fmaxf((points[3 * i + 1] - a0y) / (a1y - a0y), 0.f), 1.f);
  float z = fminf(fmaxf((points[3 * i + 2] - a0z) / (a1z - a0z), 0.f), 1.f);

  float s = lp.scale[l];
  unsigned res = lp.res[l];
  bool dense = (lp.dense[l] != 0);
  unsigned rm1 = res - 1u;
  unsigned res2 = res * res;

  float fx = x * s + 0.5f;
  float fy = y * s + 0.5f;
  float fz = z * s + 0.5f;
  float fx0 = floorf(fx), fy0 = floorf(fy), fz0 = floorf(fz);
  float wx = fx - fx0, wy = fy - fy0, wz = fz - fz0;
  unsigned bx = (unsigned)fx0, by = (unsigned)fy0, bz = (unsigned)fz0;

  const __half2* tab = tables + (size_t)l * kTableSize;

  float acc0 = 0.f, acc1 = 0.f;
  #pragma unroll
  for (int c = 0; c < 8; ++c) {
    unsigned ox = (unsigned)(c & 1);
    unsigned oy = (unsigned)((c >> 1) & 1);
    unsigned oz = (unsigned)((c >> 2) & 1);
    unsigned pcx = min(bx + ox, rm1);
    unsigned pcy = min(by + oy, rm1);
    unsigned pcz = min(bz + oz, rm1);
    unsigned idx;
    if (dense) {
      idx = pcx + pcy * res + pcz * res2;
    } else {
      idx = (pcx ^ (pcy * 2654435761u) ^ (pcz * 805459861u)) & (kTableSize - 1u);
    }
    float wt = (ox ? wx : 1.f - wx) * (oy ? wy : 1.f - wy) * (oz ? wz : 1.f - wz);
    __half2 f = tab[idx];
    acc0 += wt * __low2float(f);
    acc1 += wt * __high2float(f);
  }
  enc[(size_t)l * n + i] = __floats2half2_rn(acc0, acc1);
}

// ---------------- k2: MLP ----------------
__global__ __launch_bounds__(256)
void mlp_kernel(const __half2* __restrict__ enc,   // [L][N]
                const float* __restrict__ W1,
                const float* __restrict__ W2,
                const float* __restrict__ W3,
                float* __restrict__ out, int n)
{
  int i = blockIdx.x * blockDim.x + threadIdx.x;
  if (i >= n) return;

  float e[32];
  #pragma unroll
  for (int l = 0; l < kLevels; ++l) {
    __half2 v = enc[(size_t)l * n + i];
    e[2 * l + 0] = __low2float(v);
    e[2 * l + 1] = __high2float(v);
  }

  float h1[32];
  #pragma unroll
  for (int j = 0; j < 32; ++j) {
    float acc = 0.f;
    #pragma unroll
    for (int k = 0; k < 32; ++k) acc += e[k] * W1[32 * j + k];
    h1[j] = fmaxf(acc, 0.f);
  }
  float h2[32];
  #pragma unroll
  for (int j = 0; j < 32; ++j) {
    float acc = 0.f;
    #pragma unroll
    for (int k = 0; k < 32; ++k) acc += h1[k] * W2[32 * j + k];
    h2[j] = fmaxf(acc, 0.f);
  }
  float o[4];
  #pragma unroll
  for (int j = 0; j < 4; ++j) {
    float acc = 0.f;
    #pragma unroll
    for (int k = 0; k < 32; ++k) acc += h2[k] * W3[32 * j + k];
    o[j] = acc;
  }

  float4 r;
  r.x = 1.f / (1.f + __expf(-o[0]));
  r.y = 1.f / (1.f + __expf(-o[1]));
  r.z = 1.f / (1.f + __expf(-o[2]));
  r.w = 0.99f / (1.f + __expf(-o[3])) + 0.01f;
  reinterpret_cast<float4*>(out)[i] = r;
}

// ---------------- fallback: R0 monolithic ----------------
__global__ __launch_bounds__(256)
void hashgrid_mlp_kernel(const float* __restrict__ points,
                         const float* __restrict__ tables,
                         const float* __restrict__ W1,
                         const float* __restrict__ W2,
                         const float* __restrict__ W3,
                         const float* __restrict__ aabb,
                         float* __restrict__ out,
                         LevelParams lp, int n)
{
  int i = blockIdx.x * blockDim.x + threadIdx.x;
  if (i >= n) return;

  float a0x = aabb[0], a0y = aabb[1], a0z = aabb[2];
  float a1x = aabb[3], a1y = aabb[4], a1z = aabb[5];
  float x = fminf(fmaxf((points[3 * i + 0] - a0x) / (a1x - a0x), 0.f), 1.f);
  float y = fminf(fmaxf((points[3 * i + 1] - a0y) / (a1y - a0y), 0.f), 1.f);
  float z = fminf(fmaxf((points[3 * i + 2] - a0z) / (a1z - a0z), 0.f), 1.f);

  float enc[2 * kLevels];
  #pragma unroll
  for (int l = 0; l < kLevels; ++l) {
    float s = lp.scale[l];
    unsigned res = lp.res[l];
    bool dense = (lp.dense[l] != 0);
    unsigned rm1 = res - 1u;
    unsigned res2 = res * res;
    float fx = x * s + 0.5f, fy = y * s + 0.5f, fz = z * s + 0.5f;
    float fx0 = floorf(fx), fy0 = floorf(fy), fz0 = floorf(fz);
    float wx = fx - fx0, wy = fy - fy0, wz = fz - fz0;
    unsigned bx = (unsigned)fx0, by = (unsigned)fy0, bz = (unsigned)fz0;
    const float2* tab = reinterpret_cast<const float2*>(tables) + (size_t)l * kTableSize;
    float acc0 = 0.f, acc1 = 0.f;
    #pragma unroll
    for (int c = 0; c < 8; ++c) {
      unsigned ox = (unsigned)(c & 1);
      unsigned oy = (unsigned)((c >> 1) & 1);
      unsigned oz = (unsigned)((c >> 2) & 1);
      unsigned pcx = min(bx + ox, rm1);
      unsigned pcy = min(by + oy, rm1);
      unsigned pcz = min(bz + oz, rm1);
      unsigned idx;
      if (dense) idx = pcx + pcy * res + pcz * res2;
      else idx = (pcx ^ (pcy * 2654435761u) ^ (pcz * 805459861u)) & (kTableSize - 1u);
      float wt = (ox ? wx : 1.f - wx) * (oy ? wy : 1.f - wy) * (oz ? wz : 1.f - wz);
      float2 f = tab[idx];
      acc0 += wt * f.x;
      acc1 += wt * f.y;
    }
    enc[2 * l + 0] = acc0;
    enc[2 * l + 1] = acc1;
  }

  float h1[32];
  #pragma unroll
  for (int j = 0; j < 32; ++j) {
    float acc = 0.f;
    #pragma unroll
    for (int k = 0; k < 32; ++k) acc += enc[k] * W1[32 * j + k];
    h1[j] = fmaxf(acc, 0.f);
  }
  float h2[32];
  #pragma unroll
  for (int j = 0; j < 32; ++j) {
    float acc = 0.f;
    #pragma unroll
    for (int k = 0; k < 32; ++k) acc += h1[k] * W2[32 * j + k];
    h2[j] = fmaxf(acc, 0.f);
  }
  float o[4];
  #pragma unroll
  for (int j = 0; j < 4; ++j) {
    float acc = 0.f;
    #pragma unroll
    for (int k = 0; k < 32; ++k) acc += h2[k] * W3[32 * j + k];
    o[j] = acc;
  }

  float4 r;
  r.x = 1.f / (1.f + __expf(-o[0]));
  r.y = 1.f / (1.f + __expf(-o[1]));
  r.z = 1.f / (1.f + __expf(-o[2]));
  r.w = 0.99f / (1.f + __expf(-o[3])) + 0.01f;
  reinterpret_cast<float4*>(out)[i] = r;
}

extern "C" void kernel_launch(void* const* d_in, const int* in_sizes, int n_in,
                              void* d_out, int out_size, void* d_ws, size_t ws_size,
                              hipStream_t stream) {
  const float* points = (const float*)d_in[0];
  const float* tables = (const float*)d_in[1];
  const float* W1     = (const float*)d_in[2];
  const float* W2     = (const float*)d_in[3];
  const float* W3     = (const float*)d_in[4];
  const float* aabb   = (const float*)d_in[5];
  float* out = (float*)d_out;
  int n = in_sizes[0] / 3;

  LevelParams lp;
  const double pls = std::exp(std::log(4096.0 / 16.0) / 15.0);
  for (int l = 0; l < kLevels; ++l) {
    double s = 16.0 * std::pow(pls, (double)l) - 1.0;
    lp.scale[l] = (float)s;
    long long res = (long long)std::ceil(s) + 1;
    lp.res[l] = (unsigned)res;
    lp.dense[l] = (res * res * res <= (long long)kTableSize) ? 1 : 0;
  }

  const int block = 256;
  const size_t tab_f16_bytes = (size_t)kLevels * kTableSize * sizeof(__half2);  // 32 MB
  const size_t enc_bytes     = (size_t)kLevels * (size_t)n * sizeof(__half2);   // 128 MB
  const size_t needed = tab_f16_bytes + enc_bytes;

  if (ws_size >= needed) {
    __half2* tab_f16 = reinterpret_cast<__half2*>(d_ws);
    __half2* enc = reinterpret_cast<__half2*>((char*)d_ws + tab_f16_bytes);

    const int n_entries = kLevels * (int)kTableSize;  // 8.39M
    conv_tables_kernel<<<2048, block, 0, stream>>>(
        reinterpret_cast<const float2*>(tables), tab_f16, n_entries);

    const int bpl = (n + block - 1) / block;
    encode_kernel<<<bpl * kLevels, block, 0, stream>>>(
        points, tab_f16, aabb, enc, lp, n, bpl);

    mlp_kernel<<<(n + block - 1) / block, block, 0, stream>>>(
        enc, W1, W2, W3, out, n);
  } else {
    const int grid = (n + block - 1) / block;
    hashgrid_mlp_kernel<<<grid, block, 0, stream>>>(
        points, tables, W1, W2, W3, aabb, out, lp, n);
  }
}

// Round 3
// 909.228 us; speedup vs baseline: 1.7621x; 1.0825x over previous
//
#include <hip/hip_runtime.h>
#include <cmath>

// MLPTexture3D: 16-level hashgrid encode + 32->32->32->4 MLP.
// R2: (a) encode processes 2 points/thread (16 gathers in flight -> smooth L2
//     queue imbalance); (b) MLP uses v_dot2_f32_f16 with fp16-packed weights
//     (2 MACs/inst = 2x scalar fp32 rate); (c) conv kernel also packs weights.

namespace {
constexpr int kLevels = 16;
constexpr unsigned kTableSize = 1u << 19;

typedef _Float16 half2_t __attribute__((ext_vector_type(2)));

struct LevelParams {
  float scale[kLevels];
  unsigned res[kLevels];
  int dense[kLevels];
};
}  // namespace

// ---------------- k0: table conversion + weight packing ----------------
__global__ __launch_bounds__(256)
void conv_tables_kernel(const float2* __restrict__ src, half2_t* __restrict__ dst,
                        int n_entries,
                        const float* __restrict__ W1, const float* __restrict__ W2,
                        const float* __restrict__ W3, half2_t* __restrict__ Wh)
{
  int i = blockIdx.x * blockDim.x + threadIdx.x;
  // Weight packing: Wh = [W1h(512) | W2h(512) | W3h(64)], Wh[t] = (W[2t], W[2t+1])
  if (i < 512) {
    Wh[i] = half2_t{(_Float16)W1[2 * i], (_Float16)W1[2 * i + 1]};
  } else if (i < 1024) {
    int t = i - 512;
    Wh[512 + t] = half2_t{(_Float16)W2[2 * t], (_Float16)W2[2 * t + 1]};
  } else if (i < 1088) {
    int t = i - 1024;
    Wh[1024 + t] = half2_t{(_Float16)W3[2 * t], (_Float16)W3[2 * t + 1]};
  }
  int stride = gridDim.x * blockDim.x;
  for (; i < n_entries; i += stride) {
    float2 v = src[i];
    dst[i] = half2_t{(_Float16)v.x, (_Float16)v.y};
  }
}

// ---------------- k1: level-phased encode, 2 points/thread ----------------
__global__ __launch_bounds__(256)
void encode_kernel(const float* __restrict__ points,
                   const half2_t* __restrict__ tables,
                   const float* __restrict__ aabb,
                   half2_t* __restrict__ enc,   // [L][N]
                   LevelParams lp, int n, int bpl)
{
  int l = blockIdx.x / bpl;
  int blk = blockIdx.x - l * bpl;
  int i0 = blk * 512 + threadIdx.x;
  int i1 = i0 + 256;
  if (i0 >= n) return;
  bool validB = (i1 < n);
  int i1c = validB ? i1 : i0;

  float a0x = aabb[0], a0y = aabb[1], a0z = aabb[2];
  float a1x = aabb[3], a1y = aabb[4], a1z = aabb[5];
  float s = lp.scale[l];
  unsigned res = lp.res[l];
  bool dense = (lp.dense[l] != 0);
  unsigned rm1 = res - 1u;
  unsigned res2 = res * res;
  const half2_t* tab = tables + (size_t)l * kTableSize;

  // --- point A ---
  float xA = fminf(fmaxf((points[3 * i0 + 0] - a0x) / (a1x - a0x), 0.f), 1.f);
  float yA = fminf(fmaxf((points[3 * i0 + 1] - a0y) / (a1y - a0y), 0.f), 1.f);
  float zA = fminf(fmaxf((points[3 * i0 + 2] - a0z) / (a1z - a0z), 0.f), 1.f);
  // --- point B ---
  float xB = fminf(fmaxf((points[3 * i1c + 0] - a0x) / (a1x - a0x), 0.f), 1.f);
  float yB = fminf(fmaxf((points[3 * i1c + 1] - a0y) / (a1y - a0y), 0.f), 1.f);
  float zB = fminf(fmaxf((points[3 * i1c + 2] - a0z) / (a1z - a0z), 0.f), 1.f);

  float fxA = xA * s + 0.5f, fyA = yA * s + 0.5f, fzA = zA * s + 0.5f;
  float fxB = xB * s + 0.5f, fyB = yB * s + 0.5f, fzB = zB * s + 0.5f;
  float fx0A = floorf(fxA), fy0A = floorf(fyA), fz0A = floorf(fzA);
  float fx0B = floorf(fxB), fy0B = floorf(fyB), fz0B = floorf(fzB);
  float wxA = fxA - fx0A, wyA = fyA - fy0A, wzA = fzA - fz0A;
  float wxB = fxB - fx0B, wyB = fyB - fy0B, wzB = fzB - fz0B;
  unsigned bxA = (unsigned)fx0A, byA = (unsigned)fy0A, bzA = (unsigned)fz0A;
  unsigned bxB = (unsigned)fx0B, byB = (unsigned)fy0B, bzB = (unsigned)fz0B;

  unsigned idxA[8], idxB[8];
  float wtA[8], wtB[8];
  #pragma unroll
  for (int c = 0; c < 8; ++c) {
    unsigned ox = (unsigned)(c & 1);
    unsigned oy = (unsigned)((c >> 1) & 1);
    unsigned oz = (unsigned)((c >> 2) & 1);
    unsigned pax = min(bxA + ox, rm1), pay = min(byA + oy, rm1), paz = min(bzA + oz, rm1);
    unsigned pbx = min(bxB + ox, rm1), pby = min(byB + oy, rm1), pbz = min(bzB + oz, rm1);
    if (dense) {
      idxA[c] = pax + pay * res + paz * res2;
      idxB[c] = pbx + pby * res + pbz * res2;
    } else {
      idxA[c] = (pax ^ (pay * 2654435761u) ^ (paz * 805459861u)) & (kTableSize - 1u);
      idxB[c] = (pbx ^ (pby * 2654435761u) ^ (pbz * 805459861u)) & (kTableSize - 1u);
    }
    wtA[c] = (ox ? wxA : 1.f - wxA) * (oy ? wyA : 1.f - wyA) * (oz ? wzA : 1.f - wzA);
    wtB[c] = (ox ? wxB : 1.f - wxB) * (oy ? wyB : 1.f - wyB) * (oz ? wzB : 1.f - wzB);
  }

  // Issue all 16 loads before consuming -> 16 outstanding line requests.
  half2_t fA[8], fB[8];
  #pragma unroll
  for (int c = 0; c < 8; ++c) fA[c] = tab[idxA[c]];
  #pragma unroll
  for (int c = 0; c < 8; ++c) fB[c] = tab[idxB[c]];

  float a0 = 0.f, a1 = 0.f, b0 = 0.f, b1 = 0.f;
  #pragma unroll
  for (int c = 0; c < 8; ++c) {
    a0 += wtA[c] * (float)fA[c].x;
    a1 += wtA[c] * (float)fA[c].y;
    b0 += wtB[c] * (float)fB[c].x;
    b1 += wtB[c] * (float)fB[c].y;
  }
  enc[(size_t)l * n + i0] = half2_t{(_Float16)a0, (_Float16)a1};
  if (validB) enc[(size_t)l * n + i1] = half2_t{(_Float16)b0, (_Float16)b1};
}

// ---------------- k2: MLP with fp16 dot2 ----------------
__device__ __forceinline__ float dot2_acc(half2_t a, half2_t b, float c) {
#if __has_builtin(__builtin_amdgcn_fdot2)
  return __builtin_amdgcn_fdot2(a, b, c, false);
#else
  return c + (float)a.x * (float)b.x + (float)a.y * (float)b.y;
#endif
}

__global__ __launch_bounds__(256)
void mlp_kernel(const half2_t* __restrict__ enc,   // [L][N]
                const half2_t* __restrict__ Wh,    // [W1h 512 | W2h 512 | W3h 64]
                float* __restrict__ out, int n)
{
  int i = blockIdx.x * blockDim.x + threadIdx.x;
  if (i >= n) return;

  half2_t e[16];
  #pragma unroll
  for (int l = 0; l < kLevels; ++l) e[l] = enc[(size_t)l * n + i];

  const half2_t* W1h = Wh;
  const half2_t* W2h = Wh + 512;
  const half2_t* W3h = Wh + 1024;

  float h1f[32];
  #pragma unroll
  for (int j = 0; j < 32; ++j) {
    float acc = 0.f;
    #pragma unroll
    for (int k = 0; k < 16; ++k) acc = dot2_acc(e[k], W1h[16 * j + k], acc);
    h1f[j] = fmaxf(acc, 0.f);
  }
  half2_t h1[16];
  #pragma unroll
  for (int k = 0; k < 16; ++k)
    h1[k] = half2_t{(_Float16)h1f[2 * k], (_Float16)h1f[2 * k + 1]};

  float h2f[32];
  #pragma unroll
  for (int j = 0; j < 32; ++j) {
    float acc = 0.f;
    #pragma unroll
    for (int k = 0; k < 16; ++k) acc = dot2_acc(h1[k], W2h[16 * j + k], acc);
    h2f[j] = fmaxf(acc, 0.f);
  }
  half2_t h2[16];
  #pragma unroll
  for (int k = 0; k < 16; ++k)
    h2[k] = half2_t{(_Float16)h2f[2 * k], (_Float16)h2f[2 * k + 1]};

  float o[4];
  #pragma unroll
  for (int j = 0; j < 4; ++j) {
    float acc = 0.f;
    #pragma unroll
    for (int k = 0; k < 16; ++k) acc = dot2_acc(h2[k], W3h[16 * j + k], acc);
    o[j] = acc;
  }

  float4 r;
  r.x = 1.f / (1.f + __expf(-o[0]));
  r.y = 1.f / (1.f + __expf(-o[1]));
  r.z = 1.f / (1.f + __expf(-o[2]));
  r.w = 0.99f / (1.f + __expf(-o[3])) + 0.01f;
  reinterpret_cast<float4*>(out)[i] = r;
}

// ---------------- fallback: R0 monolithic ----------------
__global__ __launch_bounds__(256)
void hashgrid_mlp_kernel(const float* __restrict__ points,
                         const float* __restrict__ tables,
                         const float* __restrict__ W1,
                         const float* __restrict__ W2,
                         const float* __restrict__ W3,
                         const float* __restrict__ aabb,
                         float* __restrict__ out,
                         LevelParams lp, int n)
{
  int i = blockIdx.x * blockDim.x + threadIdx.x;
  if (i >= n) return;
  float a0x = aabb[0], a0y = aabb[1], a0z = aabb[2];
  float a1x = aabb[3], a1y = aabb[4], a1z = aabb[5];
  float x = fminf(fmaxf((points[3 * i + 0] - a0x) / (a1x - a0x), 0.f), 1.f);
  float y = fminf(fmaxf((points[3 * i + 1] - a0y) / (a1y - a0y), 0.f), 1.f);
  float z = fminf(fmaxf((points[3 * i + 2] - a0z) / (a1z - a0z), 0.f), 1.f);
  float enc[2 * kLevels];
  #pragma unroll
  for (int l = 0; l < kLevels; ++l) {
    float s = lp.scale[l];
    unsigned res = lp.res[l];
    bool dense = (lp.dense[l] != 0);
    unsigned rm1 = res - 1u;
    unsigned res2 = res * res;
    float fx = x * s + 0.5f, fy = y * s + 0.5f, fz = z * s + 0.5f;
    float fx0 = floorf(fx), fy0 = floorf(fy), fz0 = floorf(fz);
    float wx = fx - fx0, wy = fy - fy0, wz = fz - fz0;
    unsigned bx = (unsigned)fx0, by = (unsigned)fy0, bz = (unsigned)fz0;
    const float2* tab = reinterpret_cast<const float2*>(tables) + (size_t)l * kTableSize;
    float acc0 = 0.f, acc1 = 0.f;
    #pragma unroll
    for (int c = 0; c < 8; ++c) {
      unsigned ox = (unsigned)(c & 1);
      unsigned oy = (unsigned)((c >> 1) & 1);
      unsigned oz = (unsigned)((c >> 2) & 1);
      unsigned pcx = min(bx + ox, rm1);
      unsigned pcy = min(by + oy, rm1);
      unsigned pcz = min(bz + oz, rm1);
      unsigned idx;
      if (dense) idx = pcx + pcy * res + pcz * res2;
      else idx = (pcx ^ (pcy * 2654435761u) ^ (pcz * 805459861u)) & (kTableSize - 1u);
      float wt = (ox ? wx : 1.f - wx) * (oy ? wy : 1.f - wy) * (oz ? wz : 1.f - wz);
      float2 f = tab[idx];
      acc0 += wt * f.x;
      acc1 += wt * f.y;
    }
    enc[2 * l + 0] = acc0;
    enc[2 * l + 1] = acc1;
  }
  float h1[32];
  #pragma unroll
  for (int j = 0; j < 32; ++j) {
    float acc = 0.f;
    #pragma unroll
    for (int k = 0; k < 32; ++k) acc += enc[k] * W1[32 * j + k];
    h1[j] = fmaxf(acc, 0.f);
  }
  float h2[32];
  #pragma unroll
  for (int j = 0; j < 32; ++j) {
    float acc = 0.f;
    #pragma unroll
    for (int k = 0; k < 32; ++k) acc += h1[k] * W2[32 * j + k];
    h2[j] = fmaxf(acc, 0.f);
  }
  float o[4];
  #pragma unroll
  for (int j = 0; j < 4; ++j) {
    float acc = 0.f;
    #pragma unroll
    for (int k = 0; k < 32; ++k) acc += h2[k] * W3[32 * j + k];
    o[j] = acc;
  }
  float4 r;
  r.x = 1.f / (1.f + __expf(-o[0]));
  r.y = 1.f / (1.f + __expf(-o[1]));
  r.z = 1.f / (1.f + __expf(-o[2]));
  r.w = 0.99f / (1.f + __expf(-o[3])) + 0.01f;
  reinterpret_cast<float4*>(out)[i] = r;
}

extern "C" void kernel_launch(void* const* d_in, const int* in_sizes, int n_in,
                              void* d_out, int out_size, void* d_ws, size_t ws_size,
                              hipStream_t stream) {
  const float* points = (const float*)d_in[0];
  const float* tables = (const float*)d_in[1];
  const float* W1     = (const float*)d_in[2];
  const float* W2     = (const float*)d_in[3];
  const float* W3     = (const float*)d_in[4];
  const float* aabb   = (const float*)d_in[5];
  float* out = (float*)d_out;
  int n = in_sizes[0] / 3;

  LevelParams lp;
  const double pls = std::exp(std::log(4096.0 / 16.0) / 15.0);
  for (int l = 0; l < kLevels; ++l) {
    double s = 16.0 * std::pow(pls, (double)l) - 1.0;
    lp.scale[l] = (float)s;
    long long res = (long long)std::ceil(s) + 1;
    lp.res[l] = (unsigned)res;
    lp.dense[l] = (res * res * res <= (long long)kTableSize) ? 1 : 0;
  }

  const int block = 256;
  const size_t tab_f16_bytes = (size_t)kLevels * kTableSize * sizeof(half2_t);  // 32 MB
  const size_t enc_bytes     = (size_t)kLevels * (size_t)n * sizeof(half2_t);   // 128 MB
  const size_t w_bytes       = 1088 * sizeof(half2_t);
  const size_t needed = tab_f16_bytes + enc_bytes + w_bytes;

  if (ws_size >= needed) {
    half2_t* tab_f16 = reinterpret_cast<half2_t*>(d_ws);
    half2_t* enc = reinterpret_cast<half2_t*>((char*)d_ws + tab_f16_bytes);
    half2_t* Wh  = reinterpret_cast<half2_t*>((char*)d_ws + tab_f16_bytes + enc_bytes);

    const int n_entries = kLevels * (int)kTableSize;
    conv_tables_kernel<<<2048, block, 0, stream>>>(
        reinterpret_cast<const float2*>(tables), tab_f16, n_entries, W1, W2, W3, Wh);

    const int bpl = (n + 2 * block - 1) / (2 * block);
    encode_kernel<<<bpl * kLevels, block, 0, stream>>>(
        points, tab_f16, aabb, enc, lp, n, bpl);

    mlp_kernel<<<(n + block - 1) / block, block, 0, stream>>>(enc, Wh, out, n);
  } else {
    const int grid = (n + block - 1) / block;
    hashgrid_mlp_kernel<<<grid, block, 0, stream>>>(
        points, tables, W1, W2, W3, aabb, out, lp, n);
  }
}

// Round 4
// 768.774 us; speedup vs baseline: 2.0841x; 1.1827x over previous
//
#include <hip/hip_runtime.h>
#include <cmath>

// MLPTexture3D: 16-level hashgrid encode + 32->32->32->4 MLP.
// R3: corner-pair widened gathers. For the two corners differing in x:
//   dense:  idx1 = idx0 + 1 (same aligned 4-entry group 75%)
//   hashed: idx1 = idx0 ^ (bx^(bx+1)) -> same group 75% (bx even or bx%4==1)
// One dwordx4 (4 fp16x2 entries) at idx0&~3 covers corner0 always + corner1
// 75%; lane-masked scalar load covers the remaining 25%. Lane-address count
// per point-level drops 8 -> ~5 (addresses, not lines, are the measured
// bottleneck: 0.55 lane-addr/cyc/CU with ILP-neutral behavior in R2).

namespace {
constexpr int kLevels = 16;
constexpr unsigned kTableSize = 1u << 19;
constexpr unsigned kMask = kTableSize - 1u;

typedef _Float16 half2_t __attribute__((ext_vector_type(2)));
typedef unsigned int u32;

struct LevelParams {
  float scale[kLevels];
  unsigned res[kLevels];
  int dense[kLevels];
};
}  // namespace

// ---------------- k0: table conversion + weight packing ----------------
__global__ __launch_bounds__(256)
void conv_tables_kernel(const float2* __restrict__ src, half2_t* __restrict__ dst,
                        int n_entries,
                        const float* __restrict__ W1, const float* __restrict__ W2,
                        const float* __restrict__ W3, half2_t* __restrict__ Wh)
{
  int i = blockIdx.x * blockDim.x + threadIdx.x;
  if (i < 512) {
    Wh[i] = half2_t{(_Float16)W1[2 * i], (_Float16)W1[2 * i + 1]};
  } else if (i < 1024) {
    int t = i - 512;
    Wh[512 + t] = half2_t{(_Float16)W2[2 * t], (_Float16)W2[2 * t + 1]};
  } else if (i < 1088) {
    int t = i - 1024;
    Wh[1024 + t] = half2_t{(_Float16)W3[2 * t], (_Float16)W3[2 * t + 1]};
  }
  int stride = gridDim.x * blockDim.x;
  for (; i < n_entries; i += stride) {
    float2 v = src[i];
    dst[i] = half2_t{(_Float16)v.x, (_Float16)v.y};
  }
}

// ---------------- k1: level-phased encode, widened pair gathers ----------------
__device__ __forceinline__ u32 sel4(uint4 v, u32 j) {
  // v[j] via cndmask tree (no scratch)
  u32 lo = (j & 1u) ? v.y : v.x;
  u32 hi = (j & 1u) ? v.w : v.z;
  return (j & 2u) ? hi : lo;
}

__global__ __launch_bounds__(256)
void encode_kernel(const float* __restrict__ points,
                   const u32* __restrict__ tables,   // fp16x2 entries as u32
                   const float* __restrict__ aabb,
                   half2_t* __restrict__ enc,        // [L][N]
                   LevelParams lp, int n, int bpl)
{
  int l = blockIdx.x / bpl;
  int i = (blockIdx.x - l * bpl) * blockDim.x + threadIdx.x;
  if (i >= n) return;

  float a0x = aabb[0], a0y = aabb[1], a0z = aabb[2];
  float a1x = aabb[3], a1y = aabb[4], a1z = aabb[5];
  float x = fminf(fmaxf((points[3 * i + 0] - a0x) / (a1x - a0x), 0.f), 1.f);
  float y = fminf(fmaxf((points[3 * i + 1] - a0y) / (a1y - a0y), 0.f), 1.f);
  float z = fminf(fmaxf((points[3 * i + 2] - a0z) / (a1z - a0z), 0.f), 1.f);

  float s = lp.scale[l];
  unsigned res = lp.res[l];
  bool dense = (lp.dense[l] != 0);
  unsigned rm1 = res - 1u;
  unsigned res2 = res * res;
  const u32* tab = tables + (size_t)l * kTableSize;

  float fx = x * s + 0.5f, fy = y * s + 0.5f, fz = z * s + 0.5f;
  float fx0 = floorf(fx), fy0 = floorf(fy), fz0 = floorf(fz);
  float wx = fx - fx0, wy = fy - fy0, wz = fz - fz0;
  unsigned bx = (unsigned)fx0, by = (unsigned)fy0, bz = (unsigned)fz0;

  unsigned pcx0 = min(bx, rm1), pcx1 = min(bx + 1u, rm1);

  // 4 pairs: p = oy + 2*oz; each pair covers ox=0,1
  u32 idx0[4], idx1[4];
  #pragma unroll
  for (int p = 0; p < 4; ++p) {
    unsigned oy = (unsigned)(p & 1);
    unsigned oz = (unsigned)(p >> 1);
    unsigned pcy = min(by + oy, rm1);
    unsigned pcz = min(bz + oz, rm1);
    if (dense) {
      u32 b = pcy * res + pcz * res2;
      idx0[p] = pcx0 + b;
      idx1[p] = pcx1 + b;
    } else {
      u32 h = (pcy * 2654435761u) ^ (pcz * 805459861u);
      idx0[p] = (pcx0 ^ h) & kMask;
      idx1[p] = (pcx1 ^ h) & kMask;
    }
  }

  // Issue the 4 group loads first (ILP)
  uint4 v[4];
  #pragma unroll
  for (int p = 0; p < 4; ++p)
    v[p] = *reinterpret_cast<const uint4*>(tab + (idx0[p] & ~3u));

  // Masked fix-up loads for corner1 outside the 16B group (~25% of lanes)
  u32 e1x[4] = {0u, 0u, 0u, 0u};
  #pragma unroll
  for (int p = 0; p < 4; ++p) {
    if ((idx0[p] ^ idx1[p]) >= 4u) e1x[p] = tab[idx1[p]];
  }

  float wx1 = wx, wx0 = 1.f - wx;
  float acc0 = 0.f, acc1 = 0.f;
  #pragma unroll
  for (int p = 0; p < 4; ++p) {
    unsigned oy = (unsigned)(p & 1);
    unsigned oz = (unsigned)(p >> 1);
    float wyz = (oy ? wy : 1.f - wy) * (oz ? wz : 1.f - wz);
    u32 e0 = sel4(v[p], idx0[p] & 3u);
    u32 e1g = sel4(v[p], idx1[p] & 3u);
    u32 e1 = ((idx0[p] ^ idx1[p]) < 4u) ? e1g : e1x[p];
    half2_t f0 = __builtin_bit_cast(half2_t, e0);
    half2_t f1 = __builtin_bit_cast(half2_t, e1);
    float w0 = wyz * wx0, w1 = wyz * wx1;
    acc0 += w0 * (float)f0.x + w1 * (float)f1.x;
    acc1 += w0 * (float)f0.y + w1 * (float)f1.y;
  }
  enc[(size_t)l * n + i] = half2_t{(_Float16)acc0, (_Float16)acc1};
}

// ---------------- k2: MLP with fp16 dot2 ----------------
__device__ __forceinline__ float dot2_acc(half2_t a, half2_t b, float c) {
#if __has_builtin(__builtin_amdgcn_fdot2)
  return __builtin_amdgcn_fdot2(a, b, c, false);
#else
  return c + (float)a.x * (float)b.x + (float)a.y * (float)b.y;
#endif
}

__global__ __launch_bounds__(256)
void mlp_kernel(const half2_t* __restrict__ enc,   // [L][N]
                const half2_t* __restrict__ Wh,    // [W1h 512 | W2h 512 | W3h 64]
                float* __restrict__ out, int n)
{
  int i = blockIdx.x * blockDim.x + threadIdx.x;
  if (i >= n) return;

  half2_t e[16];
  #pragma unroll
  for (int l = 0; l < kLevels; ++l) e[l] = enc[(size_t)l * n + i];

  const half2_t* W1h = Wh;
  const half2_t* W2h = Wh + 512;
  const half2_t* W3h = Wh + 1024;

  float h1f[32];
  #pragma unroll
  for (int j = 0; j < 32; ++j) {
    float acc = 0.f;
    #pragma unroll
    for (int k = 0; k < 16; ++k) acc = dot2_acc(e[k], W1h[16 * j + k], acc);
    h1f[j] = fmaxf(acc, 0.f);
  }
  half2_t h1[16];
  #pragma unroll
  for (int k = 0; k < 16; ++k)
    h1[k] = half2_t{(_Float16)h1f[2 * k], (_Float16)h1f[2 * k + 1]};

  float h2f[32];
  #pragma unroll
  for (int j = 0; j < 32; ++j) {
    float acc = 0.f;
    #pragma unroll
    for (int k = 0; k < 16; ++k) acc = dot2_acc(h1[k], W2h[16 * j + k], acc);
    h2f[j] = fmaxf(acc, 0.f);
  }
  half2_t h2[16];
  #pragma unroll
  for (int k = 0; k < 16; ++k)
    h2[k] = half2_t{(_Float16)h2f[2 * k], (_Float16)h2f[2 * k + 1]};

  float o[4];
  #pragma unroll
  for (int j = 0; j < 4; ++j) {
    float acc = 0.f;
    #pragma unroll
    for (int k = 0; k < 16; ++k) acc = dot2_acc(h2[k], W3h[16 * j + k], acc);
    o[j] = acc;
  }

  float4 r;
  r.x = 1.f / (1.f + __expf(-o[0]));
  r.y = 1.f / (1.f + __expf(-o[1]));
  r.z = 1.f / (1.f + __expf(-o[2]));
  r.w = 0.99f / (1.f + __expf(-o[3])) + 0.01f;
  reinterpret_cast<float4*>(out)[i] = r;
}

// ---------------- fallback: R0 monolithic ----------------
__global__ __launch_bounds__(256)
void hashgrid_mlp_kernel(const float* __restrict__ points,
                         const float* __restrict__ tables,
                         const float* __restrict__ W1,
                         const float* __restrict__ W2,
                         const float* __restrict__ W3,
                         const float* __restrict__ aabb,
                         float* __restrict__ out,
                         LevelParams lp, int n)
{
  int i = blockIdx.x * blockDim.x + threadIdx.x;
  if (i >= n) return;
  float a0x = aabb[0], a0y = aabb[1], a0z = aabb[2];
  float a1x = aabb[3], a1y = aabb[4], a1z = aabb[5];
  float x = fminf(fmaxf((points[3 * i + 0] - a0x) / (a1x - a0x), 0.f), 1.f);
  float y = fminf(fmaxf((points[3 * i + 1] - a0y) / (a1y - a0y), 0.f), 1.f);
  float z = fminf(fmaxf((points[3 * i + 2] - a0z) / (a1z - a0z), 0.f), 1.f);
  float enc[2 * kLevels];
  #pragma unroll
  for (int l = 0; l < kLevels; ++l) {
    float s = lp.scale[l];
    unsigned res = lp.res[l];
    bool dense = (lp.dense[l] != 0);
    unsigned rm1 = res - 1u;
    unsigned res2 = res * res;
    float fx = x * s + 0.5f, fy = y * s + 0.5f, fz = z * s + 0.5f;
    float fx0 = floorf(fx), fy0 = floorf(fy), fz0 = floorf(fz);
    float wx = fx - fx0, wy = fy - fy0, wz = fz - fz0;
    unsigned bx = (unsigned)fx0, by = (unsigned)fy0, bz = (unsigned)fz0;
    const float2* tab = reinterpret_cast<const float2*>(tables) + (size_t)l * kTableSize;
    float acc0 = 0.f, acc1 = 0.f;
    #pragma unroll
    for (int c = 0; c < 8; ++c) {
      unsigned ox = (unsigned)(c & 1);
      unsigned oy = (unsigned)((c >> 1) & 1);
      unsigned oz = (unsigned)((c >> 2) & 1);
      unsigned pcx = min(bx + ox, rm1);
      unsigned pcy = min(by + oy, rm1);
      unsigned pcz = min(bz + oz, rm1);
      unsigned idx;
      if (dense) idx = pcx + pcy * res + pcz * res2;
      else idx = (pcx ^ (pcy * 2654435761u) ^ (pcz * 805459861u)) & kMask;
      float wt = (ox ? wx : 1.f - wx) * (oy ? wy : 1.f - wy) * (oz ? wz : 1.f - wz);
      float2 f = tab[idx];
      acc0 += wt * f.x;
      acc1 += wt * f.y;
    }
    enc[2 * l + 0] = acc0;
    enc[2 * l + 1] = acc1;
  }
  float h1[32];
  #pragma unroll
  for (int j = 0; j < 32; ++j) {
    float acc = 0.f;
    #pragma unroll
    for (int k = 0; k < 32; ++k) acc += enc[k] * W1[32 * j + k];
    h1[j] = fmaxf(acc, 0.f);
  }
  float h2[32];
  #pragma unroll
  for (int j = 0; j < 32; ++j) {
    float acc = 0.f;
    #pragma unroll
    for (int k = 0; k < 32; ++k) acc += h1[k] * W2[32 * j + k];
    h2[j] = fmaxf(acc, 0.f);
  }
  float o[4];
  #pragma unroll
  for (int j = 0; j < 4; ++j) {
    float acc = 0.f;
    #pragma unroll
    for (int k = 0; k < 32; ++k) acc += h2[k] * W3[32 * j + k];
    o[j] = acc;
  }
  float4 r;
  r.x = 1.f / (1.f + __expf(-o[0]));
  r.y = 1.f / (1.f + __expf(-o[1]));
  r.z = 1.f / (1.f + __expf(-o[2]));
  r.w = 0.99f / (1.f + __expf(-o[3])) + 0.01f;
  reinterpret_cast<float4*>(out)[i] = r;
}

extern "C" void kernel_launch(void* const* d_in, const int* in_sizes, int n_in,
                              void* d_out, int out_size, void* d_ws, size_t ws_size,
                              hipStream_t stream) {
  const float* points = (const float*)d_in[0];
  const float* tables = (const float*)d_in[1];
  const float* W1     = (const float*)d_in[2];
  const float* W2     = (const float*)d_in[3];
  const float* W3     = (const float*)d_in[4];
  const float* aabb   = (const float*)d_in[5];
  float* out = (float*)d_out;
  int n = in_sizes[0] / 3;

  LevelParams lp;
  const double pls = std::exp(std::log(4096.0 / 16.0) / 15.0);
  for (int l = 0; l < kLevels; ++l) {
    double s = 16.0 * std::pow(pls, (double)l) - 1.0;
    lp.scale[l] = (float)s;
    long long res = (long long)std::ceil(s) + 1;
    lp.res[l] = (unsigned)res;
    lp.dense[l] = (res * res * res <= (long long)kTableSize) ? 1 : 0;
  }

  const int block = 256;
  const size_t tab_f16_bytes = (size_t)kLevels * kTableSize * sizeof(half2_t);  // 32 MB
  const size_t enc_bytes     = (size_t)kLevels * (size_t)n * sizeof(half2_t);   // 128 MB
  const size_t w_bytes       = 1088 * sizeof(half2_t);
  const size_t needed = tab_f16_bytes + enc_bytes + w_bytes;

  if (ws_size >= needed) {
    half2_t* tab_f16 = reinterpret_cast<half2_t*>(d_ws);
    half2_t* enc = reinterpret_cast<half2_t*>((char*)d_ws + tab_f16_bytes);
    half2_t* Wh  = reinterpret_cast<half2_t*>((char*)d_ws + tab_f16_bytes + enc_bytes);

    const int n_entries = kLevels * (int)kTableSize;
    conv_tables_kernel<<<2048, block, 0, stream>>>(
        reinterpret_cast<const float2*>(tables), tab_f16, n_entries, W1, W2, W3, Wh);

    const int bpl = (n + block - 1) / block;
    encode_kernel<<<bpl * kLevels, block, 0, stream>>>(
        points, reinterpret_cast<const u32*>(tab_f16), aabb, enc, lp, n, bpl);

    mlp_kernel<<<(n + block - 1) / block, block, 0, stream>>>(enc, Wh, out, n);
  } else {
    const int grid = (n + block - 1) / block;
    hashgrid_mlp_kernel<<<grid, block, 0, stream>>>(
        points, tables, W1, W2, W3, aabb, out, lp, n);
  }
}